// Round 17
// baseline (1968.200 us; speedup 1.0000x reference)
//
#include <hip/hip_runtime.h>
#include <stdint.h>

// CharRNN MI355X — r16 (champion, 1675us) + K-SPLIT WAVES + 4-WAY COUNTERS.
//   r16 post-mortem: LDS-resident proj/x −6.4%. Remaining chain terms
//   attacked here:
//   (1) K-split: wave wv consumes kb in [8wv,8wv+8) for ALL 4 nt-slices
//       -> A-panel read ONCE per CU (32 b128 vs 128; −~850cy LDS pipe),
//       partials reduced via f32x4 zones in the staging-freed LDS (all 4
//       zones written, incl. own -> no runtime-indexed register arrays).
//   (2) 4-way split barrier counters (gj&3, 128B apart): 4 serialized RMWs
//       per line instead of 16; wave0 lanes 0-3 poll all 4 in one RTT.
//   Everything else byte-identical to r16: reg-resident W_hh B-frags,
//   h_lds stride-2064, LDS proj (64x65) + transposed x, 16x64 geometry,
//   split MALL barrier + logits window, ftanh, packed publish, wof table.
// d_ws: proj f32 @0 (256KB) | cnt @262144 (256KB, 8448B group stride,
//       4 sub-counters x 128B) | wof @524288 (128KB) | ring bf16 @1MB (16MB)

#define BATCH 256
#define SEQ   512
#define HID   1024
#define VOC   64
#define EMB   256
#define FINAL_OFF (BATCH * SEQ * VOC)   // 8388608
#define RING_SLOTS 32
#define BH (BATCH * HID)
#define CNT_STRIDE 8448

typedef __attribute__((ext_vector_type(8))) short short8;
typedef __attribute__((ext_vector_type(4))) float f32x4;
typedef unsigned long long u64;

__device__ inline unsigned short f2bf(float f) {
  union { float f; unsigned u; } v; v.f = f;
  unsigned u = v.u;
  return (unsigned short)((u + 0x7FFFu + ((u >> 16) & 1u)) >> 16);  // RNE
}

// branch-free tanh: 1 - 2/(e^{2x}+1). Verified r7+.
__device__ __forceinline__ float ftanh(float v) {
  float e = __expf(2.0f * v);
  return fmaf(-2.0f, __builtin_amdgcn_rcpf(e + 1.0f), 1.0f);
}

// ---- agent-scope (MALL-point) ops — the PROVEN coherence class -------------
__device__ inline u64 cload64(const unsigned short* p) {
  return __hip_atomic_load((const u64*)p, __ATOMIC_RELAXED,
                           __HIP_MEMORY_SCOPE_AGENT);
}
__device__ inline void cstore32(unsigned short* p, unsigned v) {
  __hip_atomic_store((unsigned*)p, v, __ATOMIC_RELAXED,
                     __HIP_MEMORY_SCOPE_AGENT);
}

// ---------------- K1: projection table -------------------------------------
__global__ __launch_bounds__(256) void k_prep(const float* __restrict__ emb,
                                              const float* __restrict__ Wih,
                                              const float* __restrict__ bh,
                                              float* __restrict__ proj) {
  __shared__ float es[EMB];
  const int v = blockIdx.x >> 2;        // 0..63
  const int p = blockIdx.x & 3;         // h-quarter
  const int tid = threadIdx.x;
  es[tid] = emb[v * EMB + tid];
  __syncthreads();
  const int h = p * 256 + tid;
  float acc = bh[h];
  for (int e = 0; e < EMB; ++e) acc += es[e] * Wih[e * HID + h];
  proj[v * HID + h] = acc;
}

// ---------------- K1b: W_ho bf16 fragment table (r6+-proven) ----------------
// entry e = ((kb*4+q)*4+vt)*16 + l15 ; elems j: Who[(kb*32+q*8+j)*VOC+vt*16+l15]
__global__ __launch_bounds__(256) void k_prep2(const float* __restrict__ Who,
                                               unsigned short* __restrict__ wof) {
  const int e = blockIdx.x * 256 + threadIdx.x;   // 0..8191
  const int l15 = e & 15, vt = (e >> 4) & 3, qq = (e >> 6) & 3, kb = e >> 8;
  #pragma unroll
  for (int j = 0; j < 8; ++j)
    wof[e * 8 + j] = f2bf(Who[(kb * 32 + qq * 8 + j) * VOC + vt * 16 + l15]);
}

// ---------------- K2: persistent recurrence + inline logits ----------------
// LDS 131072: W_hh B-frag staging (dies) ->
//   h_lds @0      16 x 2064B = 33024  (floor-8 A-reads)
//   p_lds @33024  64 x 65 f32 = 16640
//   xs_t  @49664  512 x 16 int = 32768
//   red   @82432  16 zones x 64 lanes x 16B = 16384 (K-split partials)
__global__ __launch_bounds__(256, 1) void k_rnn(
    const int* __restrict__ x, const float* __restrict__ Whh,
    const float* __restrict__ proj, const unsigned short* __restrict__ wof,
    const float* __restrict__ bo, unsigned short* __restrict__ ring,
    float* __restrict__ out, float* __restrict__ final_out,
    unsigned int* __restrict__ cnt) {
  extern __shared__ char smem[];
  unsigned short* w_lds = (unsigned short*)smem;            // staging (dies)
  char*           h_lds = smem;                             // @0
  float*          p_lds = (float*)(smem + 33024);           // @33024
  int*            xs_t  = (int*)(smem + 49664);             // @49664
  char*           red   = smem + 82432;                     // @82432

  const int tid = threadIdx.x, bid = blockIdx.x;
  const int gi = bid & 15, gj = bid >> 4;   // group (16 rows) / col-slice (64)
  const int row0 = gi * 16;
  const int lane = tid & 63, wv = tid >> 6;                 // wv = K-quarter
  const int l15 = lane & 15, q = lane >> 4;

  // W_hh column slice (1024 x 64) -> LDS bf16 B-fragment order (staging).
  for (int it = 0; it < 256; ++it) {
    int u = it * 256 + tid;               // 0..65535
    int k = u >> 6, n = u & 63;           // coalesced over n
    int kb = k >> 5, qq = (k >> 3) & 3, j8 = k & 7;
    w_lds[(size_t)kb * 2048 + qq * 512 + n * 8 + j8] =
        f2bf(Whh[k * HID + gj * 64 + n]);
  }
  __syncthreads();

  // B-fragments -> REGISTERS: wave wv holds kb in [8wv,8wv+8) x 4 nt-slices.
  short8 bfr[32];                         // [i*4+nt], 128 VGPR
  {
    const char* bsta = (const char*)w_lds + q * 1024 + l15 * 16;
    #pragma unroll
    for (int i = 0; i < 8; ++i)
      #pragma unroll
      for (int nt = 0; nt < 4; ++nt)
        bfr[i * 4 + nt] =
            *(const short8*)(bsta + (size_t)(wv * 8 + i) * 4096 + nt * 256);
  }
  __syncthreads();                        // staging dead; region repurposed

  // LDS-resident proj slice (64 vocab x 64 cols, padded row 65 floats).
  for (int it = 0; it < 16; ++it) {
    int u = it * 256 + tid;               // 0..4095
    int v = u >> 6, c = u & 63;
    p_lds[v * 65 + c] = proj[(size_t)v * HID + gj * 64 + c];
  }
  // LDS-resident transposed x slice: xs_t[t][row].
  for (int it = 0; it < 32; ++it) {
    int u = it * 256 + tid;               // 0..8191
    int tt = u >> 4, r = u & 15;
    xs_t[tt * 16 + r] = x[(size_t)(row0 + r) * SEQ + tt];
  }
  __syncthreads();

  // 4-way split counters: group base + (gj&3)*128B; targets 4*(t+1) each.
  unsigned int* cnt_g = (unsigned int*)((char*)cnt + gi * CNT_STRIDE);
  unsigned int* cnt_a = cnt_g + (gj & 3) * 32;

  const int hcol = gj * 64 + wv * 16 + l15;
  const int pcol = wv * 16 + l15;                   // col within p_lds row
  const char* abase = h_lds + l15 * 2064 + q * 16;
  const float bias = bo[wv * 16 + l15];
  const char* wofb = (const char*)wof + ((q * 4 + wv) * 16 + l15) * 16;

  for (int t = 0; t < SEQ; ++t) {
    // 1) recurrence, K-split: wave wv does kb in [8wv,8wv+8) for ALL nt.
    f32x4 p0 = {0.f, 0.f, 0.f, 0.f}, p1 = {0.f, 0.f, 0.f, 0.f};
    f32x4 p2 = {0.f, 0.f, 0.f, 0.f}, p3 = {0.f, 0.f, 0.f, 0.f};
    if (t > 0) {
      #pragma unroll
      for (int i = 0; i < 8; ++i) {
        short8 af = *(const short8*)(abase + (wv * 8 + i) * 64);
        p0 = __builtin_amdgcn_mfma_f32_16x16x32_bf16(af, bfr[i * 4 + 0], p0, 0, 0, 0);
        p1 = __builtin_amdgcn_mfma_f32_16x16x32_bf16(af, bfr[i * 4 + 1], p1, 0, 0, 0);
        p2 = __builtin_amdgcn_mfma_f32_16x16x32_bf16(af, bfr[i * 4 + 2], p2, 0, 0, 0);
        p3 = __builtin_amdgcn_mfma_f32_16x16x32_bf16(af, bfr[i * 4 + 3], p3, 0, 0, 0);
      }
    }
    // cross-wave reduce: write ALL 4 zones (w=wv, nt), sync, read nt=wv.
    {
      char* zb = red + ((size_t)(wv * 4) * 64 + lane) * 16;
      *(f32x4*)(zb)        = p0;
      *(f32x4*)(zb + 1024) = p1;          // zone stride = 64 lanes*16B
      *(f32x4*)(zb + 2048) = p2;
      *(f32x4*)(zb + 3072) = p3;
    }
    __syncthreads();
    f32x4 s;
    {
      const char* rb = red + ((size_t)wv * 64 + lane) * 16;   // (w=0, nt=wv)
      f32x4 s0 = *(const f32x4*)(rb);
      f32x4 s1 = *(const f32x4*)(rb + 4096);                  // w=1
      f32x4 s2 = *(const f32x4*)(rb + 8192);                  // w=2
      f32x4 s3 = *(const f32x4*)(rb + 12288);                 // w=3
      s = (s0 + s1) + (s2 + s3);
    }
    // 2) epilogue: h_t = tanh(proj[x_t] + acc) — operands in LDS/regs.
    unsigned short* slot = ring + (size_t)(t & (RING_SLOTS - 1)) * BH;
    float hv[4];
    #pragma unroll
    for (int r = 0; r < 4; ++r) {
      int row = q * 4 + r;                                  // D row
      int xi = xs_t[t * 16 + row];                          // LDS broadcast
      hv[r] = ftanh(p_lds[xi * 65 + pcol] + s[r]);
      if (t == SEQ - 1) final_out[(size_t)(row0 + row) * HID + hcol] = hv[r];
    }
    #pragma unroll
    for (int r = 0; r < 4; ++r) {
      unsigned myb = f2bf(hv[r]);
      unsigned oth = (unsigned)__shfl_xor((int)myb, 1);
      if ((l15 & 1) == 0) {
        int b = row0 + q * 4 + r;
        cstore32(slot + (size_t)b * HID + hcol, myb | (oth << 16));
      }
    }
    // 3) barrier arrive: drain, then one add to this block's sub-counter.
    __syncthreads();                      // release: vmcnt(0) drain
    if (tid == 0) atomicAdd(cnt_a, 1u);
    // 4) logits lump in the barrier window: tsel <= t-1 (visible since the
    //    PREVIOUS round completed). Slot hazard: t - tsel in [1,16] < 32.
    if ((t & 15) == 15) {
      int tsel = (t - 16) + gj;
      if (tsel >= 0) {
        const unsigned short* hs =
            ring + (size_t)(tsel & (RING_SLOTS - 1)) * BH +
            (size_t)(row0 + l15) * HID + q * 8;             // A row base
        f32x4 lc = {0.f, 0.f, 0.f, 0.f};
        for (int g = 0; g < 4; ++g) {
          u64 hb[16];
          #pragma unroll
          for (int j = 0; j < 8; ++j) {
            const unsigned short* pk = hs + (g * 8 + j) * 32;
            hb[2 * j]     = cload64(pk);
            hb[2 * j + 1] = cload64(pk + 4);
          }
          #pragma unroll
          for (int j = 0; j < 8; ++j) {
            union { u64 d[2]; short8 s8; } c;
            c.d[0] = hb[2 * j]; c.d[1] = hb[2 * j + 1];
            short8 w8 = *(const short8*)(wofb + (size_t)(g * 8 + j) * 4096);
            lc = __builtin_amdgcn_mfma_f32_16x16x32_bf16(c.s8, w8, lc, 0, 0, 0);
          }
        }
        #pragma unroll
        for (int rr = 0; rr < 4; ++rr) {
          int b = row0 + q * 4 + rr;
          out[((size_t)b * SEQ + tsel) * VOC + wv * 16 + l15] = lc[rr] + bias;
        }
      }
    }
    // barrier wait: wave0 lanes 0..3 poll the 4 sub-counters in parallel.
    if (tid < 64) {
      const unsigned* cp = cnt_g + tid * 32;   // lanes 0..3 meaningful
      int g = 0;
      for (;;) {
        int cond = 1;
        if (tid < 4)
          cond = (__hip_atomic_load(cp, __ATOMIC_RELAXED,
                                    __HIP_MEMORY_SCOPE_AGENT)
                  >= 4u * (unsigned)(t + 1));
        if (__all(cond)) break;
        __builtin_amdgcn_s_sleep(1);
        if (++g > (1 << 16)) break;      // bailout: wrong answer beats a hang
      }
    }
    __syncthreads();                      // acquire broadcast
    // 5) restage h_t (16 rows x 1024, coalesced agent loads) -> h_lds (2064)
    if (t < SEQ - 1) {
      u64 tmp[16];
      #pragma unroll
      for (int rr = 0; rr < 16; ++rr)
        tmp[rr] = cload64(slot + (size_t)(row0 + rr) * HID + tid * 4);
      #pragma unroll
      for (int rr = 0; rr < 16; ++rr)
        *(u64*)(h_lds + rr * 2064 + tid * 8) = tmp[rr];
      __syncthreads();
    }
  }

  // ---- tail: tsel = 511 (only gj==15). Barrier round 512 completed, so
  //      slot 511 is globally visible; no extra wait needed.
  if (gj == 15) {
    int tsel = SEQ - 1;
    const unsigned short* hs =
        ring + (size_t)(tsel & (RING_SLOTS - 1)) * BH +
        (size_t)(row0 + l15) * HID + q * 8;
    f32x4 lc = {0.f, 0.f, 0.f, 0.f};
    for (int g = 0; g < 4; ++g) {
      u64 hb[16];
      #pragma unroll
      for (int j = 0; j < 8; ++j) {
        const unsigned short* pk = hs + (g * 8 + j) * 32;
        hb[2 * j]     = cload64(pk);
        hb[2 * j + 1] = cload64(pk + 4);
      }
      #pragma unroll
      for (int j = 0; j < 8; ++j) {
        union { u64 d[2]; short8 s8; } c;
        c.d[0] = hb[2 * j]; c.d[1] = hb[2 * j + 1];
        short8 w8 = *(const short8*)(wofb + (size_t)(g * 8 + j) * 4096);
        lc = __builtin_amdgcn_mfma_f32_16x16x32_bf16(c.s8, w8, lc, 0, 0, 0);
      }
    }
    #pragma unroll
    for (int rr = 0; rr < 4; ++rr) {
      int b = row0 + q * 4 + rr;
      out[((size_t)b * SEQ + tsel) * VOC + wv * 16 + l15] = lc[rr] + bias;
    }
  }
}

// ---------------- launch ----------------------------------------------------
extern "C" void kernel_launch(void* const* d_in, const int* in_sizes, int n_in,
                              void* d_out, int out_size, void* d_ws, size_t ws_size,
                              hipStream_t stream) {
  const int*   x   = (const int*)d_in[0];
  const float* emb = (const float*)d_in[1];
  const float* Wih = (const float*)d_in[2];
  const float* Whh = (const float*)d_in[3];
  const float* bh  = (const float*)d_in[4];
  const float* Who = (const float*)d_in[5];
  const float* bo  = (const float*)d_in[6];
  float* out = (float*)d_out;

  char* ws = (char*)d_ws;
  float*          proj = (float*)ws;                         // 262144 B
  unsigned int*   cnt  = (unsigned int*)(ws + 262144);       // 256KB region
  unsigned short* wof  = (unsigned short*)(ws + 524288);     // 131072 B
  unsigned short* ring = (unsigned short*)(ws + (1 << 20));  // 16 MiB

  size_t need = (size_t)(1 << 20) + (size_t)RING_SLOTS * BATCH * HID * 2;
  if (ws_size < need) return;  // diagnostic fail (absmax) instead of a fault

  (void)hipFuncSetAttribute(reinterpret_cast<const void*>(k_rnn),
                            hipFuncAttributeMaxDynamicSharedMemorySize, 131072);

  k_prep<<<256, 256, 0, stream>>>(emb, Wih, bh, proj);
  k_prep2<<<32, 256, 0, stream>>>(Who, wof);
  hipMemsetAsync(cnt, 0, 262144, stream);
  k_rnn<<<256, 256, 131072, stream>>>(x, Whh, proj, wof, bo, ring,
                                      out, out + FINAL_OFF, cnt);
}

// Round 18
// 1708.605 us; speedup vs baseline: 1.1519x; 1.1519x over previous
//
#include <hip/hip_runtime.h>
#include <stdint.h>

// CharRNN MI355X — r16 champion RESTORED (1675us).
//   r17 post-mortem: K-split predicted-and-achieved the conflict drop
//   (7.26e7 -> 2.23e7) yet REGRESSED 15% — LDS-pipe/bank-conflict cost is
//   overlapped (off-path); the K-split's extra intra-block reduce rendezvous
//   (partials->LDS->sync->read) is on-path (+490cy/step). Reverted.
//   Final structure (levers that PROVED on-path, all retained):
//     r13: W_hh B-frags register-resident (128 VGPR)        −18%
//     r16: proj (64x65 padded) + transposed x in LDS        −6.4%
//     r7:  ftanh exp identity; 4-chain accumulators
//     r12: logits lump inside the barrier arrive/wait window
//     r0/r8: agent-scope ring + single atomicAdd counter barrier
//   Probed and off-path (removed/never re-added): XCD-local data (r14),
//   flag barriers (r4/r11), counter spreading (r12), K-split (r17),
//   last-arriver fast path (r15), paced logits (r7).
// d_ws: proj f32 @0 (256KB) | cnt @262144 (256KB, 8448B stride) |
//       wof @524288 (128KB) | ring bf16 @1MB (16MB)

#define BATCH 256
#define SEQ   512
#define HID   1024
#define VOC   64
#define EMB   256
#define FINAL_OFF (BATCH * SEQ * VOC)   // 8388608
#define RING_SLOTS 32
#define BH (BATCH * HID)
#define CNT_STRIDE 8448

typedef __attribute__((ext_vector_type(8))) short short8;
typedef __attribute__((ext_vector_type(4))) float f32x4;
typedef unsigned long long u64;

__device__ inline unsigned short f2bf(float f) {
  union { float f; unsigned u; } v; v.f = f;
  unsigned u = v.u;
  return (unsigned short)((u + 0x7FFFu + ((u >> 16) & 1u)) >> 16);  // RNE
}

// branch-free tanh: 1 - 2/(e^{2x}+1). Verified r7+.
__device__ __forceinline__ float ftanh(float v) {
  float e = __expf(2.0f * v);
  return fmaf(-2.0f, __builtin_amdgcn_rcpf(e + 1.0f), 1.0f);
}

// ---- agent-scope (MALL-point) ops — the PROVEN coherence class -------------
__device__ inline u64 cload64(const unsigned short* p) {
  return __hip_atomic_load((const u64*)p, __ATOMIC_RELAXED,
                           __HIP_MEMORY_SCOPE_AGENT);
}
__device__ inline void cstore32(unsigned short* p, unsigned v) {
  __hip_atomic_store((unsigned*)p, v, __ATOMIC_RELAXED,
                     __HIP_MEMORY_SCOPE_AGENT);
}

// ---------------- K1: projection table -------------------------------------
__global__ __launch_bounds__(256) void k_prep(const float* __restrict__ emb,
                                              const float* __restrict__ Wih,
                                              const float* __restrict__ bh,
                                              float* __restrict__ proj) {
  __shared__ float es[EMB];
  const int v = blockIdx.x >> 2;        // 0..63
  const int p = blockIdx.x & 3;         // h-quarter
  const int tid = threadIdx.x;
  es[tid] = emb[v * EMB + tid];
  __syncthreads();
  const int h = p * 256 + tid;
  float acc = bh[h];
  for (int e = 0; e < EMB; ++e) acc += es[e] * Wih[e * HID + h];
  proj[v * HID + h] = acc;
}

// ---------------- K1b: W_ho bf16 fragment table (r6+-proven) ----------------
// entry e = ((kb*4+q)*4+vt)*16 + l15 ; elems j: Who[(kb*32+q*8+j)*VOC+vt*16+l15]
__global__ __launch_bounds__(256) void k_prep2(const float* __restrict__ Who,
                                               unsigned short* __restrict__ wof) {
  const int e = blockIdx.x * 256 + threadIdx.x;   // 0..8191
  const int l15 = e & 15, vt = (e >> 4) & 3, qq = (e >> 6) & 3, kb = e >> 8;
  #pragma unroll
  for (int j = 0; j < 8; ++j)
    wof[e * 8 + j] = f2bf(Who[(kb * 32 + qq * 8 + j) * VOC + vt * 16 + l15]);
}

// ---------------- K2: persistent recurrence + inline logits ----------------
// LDS 131072: W_hh B-frag staging (dies) ->
//   h_lds @0      16 x 2064B = 33024  (bank-clean A-reads)
//   p_lds @33024  64 x 65 f32 = 16640 (padded vs q-group alias)
//   xs_t  @49664  512 x 16 int = 32768 (transposed x, conflict-free)
__global__ __launch_bounds__(256, 1) void k_rnn(
    const int* __restrict__ x, const float* __restrict__ Whh,
    const float* __restrict__ proj, const unsigned short* __restrict__ wof,
    const float* __restrict__ bo, unsigned short* __restrict__ ring,
    float* __restrict__ out, float* __restrict__ final_out,
    unsigned int* __restrict__ cnt) {
  extern __shared__ char smem[];
  unsigned short* w_lds = (unsigned short*)smem;            // staging (dies)
  char*           h_lds = smem;                             // @0
  float*          p_lds = (float*)(smem + 33024);           // @33024
  int*            xs_t  = (int*)(smem + 49664);             // @49664

  const int tid = threadIdx.x, bid = blockIdx.x;
  const int gi = bid & 15, gj = bid >> 4;   // group (16 rows) / col-slice (64)
  const int row0 = gi * 16;
  const int lane = tid & 63, wv = tid >> 6;                 // wv = nt slice
  const int l15 = lane & 15, q = lane >> 4;

  // W_hh column slice (1024 x 64) -> LDS bf16 B-fragment order (staging).
  for (int it = 0; it < 256; ++it) {
    int u = it * 256 + tid;               // 0..65535
    int k = u >> 6, n = u & 63;           // coalesced over n
    int kb = k >> 5, qq = (k >> 3) & 3, j8 = k & 7;
    w_lds[(size_t)kb * 2048 + qq * 512 + n * 8 + j8] =
        f2bf(Whh[k * HID + gj * 64 + n]);
  }
  __syncthreads();

  // B-fragments -> REGISTERS (once; W_hh is step-invariant). 128 VGPR.
  short8 bfr[32];
  {
    const char* bbase = (const char*)w_lds + q * 1024 + (wv * 16 + l15) * 16;
    #pragma unroll
    for (int kb = 0; kb < 32; ++kb)
      bfr[kb] = *(const short8*)(bbase + (size_t)kb * 4096);
  }
  __syncthreads();                        // staging dead; region repurposed

  // LDS-resident proj slice (64 vocab x 64 cols, padded row 65 floats).
  for (int it = 0; it < 16; ++it) {
    int u = it * 256 + tid;               // 0..4095
    int v = u >> 6, c = u & 63;
    p_lds[v * 65 + c] = proj[(size_t)v * HID + gj * 64 + c];
  }
  // LDS-resident transposed x slice: xs_t[t][row].
  for (int it = 0; it < 32; ++it) {
    int u = it * 256 + tid;               // 0..8191
    int tt = u >> 4, r = u & 15;
    xs_t[tt * 16 + r] = x[(size_t)(row0 + r) * SEQ + tt];
  }
  __syncthreads();

  unsigned int* cnt_i = (unsigned int*)((char*)cnt + gi * CNT_STRIDE);

  const int hcol = gj * 64 + wv * 16 + l15;
  const int pcol = wv * 16 + l15;                   // col within p_lds row
  const char* abase = h_lds + l15 * 2064 + q * 16;  // stride 2064: bank-clean
  const float bias = bo[wv * 16 + l15];
  const char* wofb = (const char*)wof + ((q * 4 + wv) * 16 + l15) * 16;

  for (int t = 0; t < SEQ; ++t) {
    // 1) recurrence MFMA: 16x16 tile, K=1024; A from LDS, B from registers.
    f32x4 a0 = {0.f, 0.f, 0.f, 0.f}, a1 = {0.f, 0.f, 0.f, 0.f};
    f32x4 a2 = {0.f, 0.f, 0.f, 0.f}, a3 = {0.f, 0.f, 0.f, 0.f};
    if (t > 0) {
      #pragma unroll
      for (int kb = 0; kb < 32; kb += 4) {
        short8 af0 = *(const short8*)(abase + (kb + 0) * 64);
        a0 = __builtin_amdgcn_mfma_f32_16x16x32_bf16(af0, bfr[kb + 0], a0, 0, 0, 0);
        short8 af1 = *(const short8*)(abase + (kb + 1) * 64);
        a1 = __builtin_amdgcn_mfma_f32_16x16x32_bf16(af1, bfr[kb + 1], a1, 0, 0, 0);
        short8 af2 = *(const short8*)(abase + (kb + 2) * 64);
        a2 = __builtin_amdgcn_mfma_f32_16x16x32_bf16(af2, bfr[kb + 2], a2, 0, 0, 0);
        short8 af3 = *(const short8*)(abase + (kb + 3) * 64);
        a3 = __builtin_amdgcn_mfma_f32_16x16x32_bf16(af3, bfr[kb + 3], a3, 0, 0, 0);
      }
    }
    // 2) epilogue: h_t = tanh(proj[x_t] + acc) — ALL operands in LDS/regs.
    unsigned short* slot = ring + (size_t)(t & (RING_SLOTS - 1)) * BH;
    float hv[4];
    #pragma unroll
    for (int r = 0; r < 4; ++r) {
      int row = q * 4 + r;                                  // D row
      int xi = xs_t[t * 16 + row];                          // LDS broadcast
      float av = (a0[r] + a1[r]) + (a2[r] + a3[r]);
      hv[r] = ftanh(p_lds[xi * 65 + pcol] + av);
      if (t == SEQ - 1) final_out[(size_t)(row0 + row) * HID + hcol] = hv[r];
    }
    #pragma unroll
    for (int r = 0; r < 4; ++r) {
      unsigned myb = f2bf(hv[r]);
      unsigned oth = (unsigned)__shfl_xor((int)myb, 1);
      if ((l15 & 1) == 0) {
        int b = row0 + q * 4 + r;
        cstore32(slot + (size_t)b * HID + hcol, myb | (oth << 16));
      }
    }
    // 3) barrier arrive (drain + atomicAdd), then logits window, then wait.
    __syncthreads();                      // release: vmcnt(0) drain
    if (tid == 0) atomicAdd(cnt_i, 1u);
    // 4) logits lump in the barrier window: tsel <= t-1 (visible since the
    //    PREVIOUS round completed). Slot hazard: t - tsel in [1,16] < 32.
    if ((t & 15) == 15) {
      int tsel = (t - 16) + gj;
      if (tsel >= 0) {
        const unsigned short* hs =
            ring + (size_t)(tsel & (RING_SLOTS - 1)) * BH +
            (size_t)(row0 + l15) * HID + q * 8;             // A row base
        f32x4 lc = {0.f, 0.f, 0.f, 0.f};
        for (int g = 0; g < 4; ++g) {
          u64 hb[16];
          #pragma unroll
          for (int j = 0; j < 8; ++j) {
            const unsigned short* pk = hs + (g * 8 + j) * 32;
            hb[2 * j]     = cload64(pk);
            hb[2 * j + 1] = cload64(pk + 4);
          }
          #pragma unroll
          for (int j = 0; j < 8; ++j) {
            union { u64 d[2]; short8 s8; } c;
            c.d[0] = hb[2 * j]; c.d[1] = hb[2 * j + 1];
            short8 w8 = *(const short8*)(wofb + (size_t)(g * 8 + j) * 4096);
            lc = __builtin_amdgcn_mfma_f32_16x16x32_bf16(c.s8, w8, lc, 0, 0, 0);
          }
        }
        #pragma unroll
        for (int rr = 0; rr < 4; ++rr) {
          int b = row0 + q * 4 + rr;
          out[((size_t)b * SEQ + tsel) * VOC + wv * 16 + l15] = lc[rr] + bias;
        }
      }
    }
    // barrier wait
    if (tid == 0) {
      int guard = 0;
      while (__hip_atomic_load(cnt_i, __ATOMIC_RELAXED,
                               __HIP_MEMORY_SCOPE_AGENT)
             < 16u * (unsigned)(t + 1)) {
        __builtin_amdgcn_s_sleep(1);
        if (++guard > (1 << 16)) break;  // bailout: wrong answer beats a hang
      }
    }
    __syncthreads();                      // acquire broadcast
    // 5) restage h_t (16 rows x 1024, coalesced agent loads) -> h_lds (2064)
    if (t < SEQ - 1) {
      u64 tmp[16];
      #pragma unroll
      for (int rr = 0; rr < 16; ++rr)
        tmp[rr] = cload64(slot + (size_t)(row0 + rr) * HID + tid * 4);
      #pragma unroll
      for (int rr = 0; rr < 16; ++rr)
        *(u64*)(h_lds + rr * 2064 + tid * 8) = tmp[rr];
      __syncthreads();
    }
  }

  // ---- tail: tsel = 511 (only gj==15). Barrier round 512 completed, so
  //      slot 511 is globally visible; no extra wait needed.
  if (gj == 15) {
    int tsel = SEQ - 1;
    const unsigned short* hs =
        ring + (size_t)(tsel & (RING_SLOTS - 1)) * BH +
        (size_t)(row0 + l15) * HID + q * 8;
    f32x4 lc = {0.f, 0.f, 0.f, 0.f};
    for (int g = 0; g < 4; ++g) {
      u64 hb[16];
      #pragma unroll
      for (int j = 0; j < 8; ++j) {
        const unsigned short* pk = hs + (g * 8 + j) * 32;
        hb[2 * j]     = cload64(pk);
        hb[2 * j + 1] = cload64(pk + 4);
      }
      #pragma unroll
      for (int j = 0; j < 8; ++j) {
        union { u64 d[2]; short8 s8; } c;
        c.d[0] = hb[2 * j]; c.d[1] = hb[2 * j + 1];
        short8 w8 = *(const short8*)(wofb + (size_t)(g * 8 + j) * 4096);
        lc = __builtin_amdgcn_mfma_f32_16x16x32_bf16(c.s8, w8, lc, 0, 0, 0);
      }
    }
    #pragma unroll
    for (int rr = 0; rr < 4; ++rr) {
      int b = row0 + q * 4 + rr;
      out[((size_t)b * SEQ + tsel) * VOC + wv * 16 + l15] = lc[rr] + bias;
    }
  }
}

// ---------------- launch ----------------------------------------------------
extern "C" void kernel_launch(void* const* d_in, const int* in_sizes, int n_in,
                              void* d_out, int out_size, void* d_ws, size_t ws_size,
                              hipStream_t stream) {
  const int*   x   = (const int*)d_in[0];
  const float* emb = (const float*)d_in[1];
  const float* Wih = (const float*)d_in[2];
  const float* Whh = (const float*)d_in[3];
  const float* bh  = (const float*)d_in[4];
  const float* Who = (const float*)d_in[5];
  const float* bo  = (const float*)d_in[6];
  float* out = (float*)d_out;

  char* ws = (char*)d_ws;
  float*          proj = (float*)ws;                         // 262144 B
  unsigned int*   cnt  = (unsigned int*)(ws + 262144);       // 256KB region
  unsigned short* wof  = (unsigned short*)(ws + 524288);     // 131072 B
  unsigned short* ring = (unsigned short*)(ws + (1 << 20));  // 16 MiB

  size_t need = (size_t)(1 << 20) + (size_t)RING_SLOTS * BATCH * HID * 2;
  if (ws_size < need) return;  // diagnostic fail (absmax) instead of a fault

  (void)hipFuncSetAttribute(reinterpret_cast<const void*>(k_rnn),
                            hipFuncAttributeMaxDynamicSharedMemorySize, 131072);

  k_prep<<<256, 256, 0, stream>>>(emb, Wih, bh, proj);
  k_prep2<<<32, 256, 0, stream>>>(Who, wof);
  hipMemsetAsync(cnt, 0, 262144, stream);
  k_rnn<<<256, 256, 131072, stream>>>(x, Whh, proj, wof, bo, ring,
                                      out, out + FINAL_OFF, cnt);
}